// Round 6
// baseline (70.600 us; speedup 1.0000x reference)
//
#include <hip/hip_runtime.h>
#include <hip/hip_bf16.h>
#include <hip/hip_fp16.h>

#define SEQ    2048
#define DMODEL 512
#define NH     8
#define QBLK   128   /* 4 waves x 32 q-rows */
#define KVB    64
#define NT     (SEQ / KVB)
#define NT_H   (NT / 2)          /* tiles per KV half */

#if __has_builtin(__builtin_amdgcn_exp2f)
#define EXPFN(x) __builtin_amdgcn_exp2f(x)
#define QSCALE 0.18033688011112042f   /* 0.125 * log2(e) */
#else
#define EXPFN(x) __expf(x)
#define QSCALE 0.125f
#endif
#define THR 8.0f

typedef __attribute__((ext_vector_type(8)))  short     bf16x8;
typedef __attribute__((ext_vector_type(16))) float     f32x16;
typedef __attribute__((ext_vector_type(2)))  int       i32x2;
typedef __attribute__((ext_vector_type(4)))  _Float16  f16x4;
typedef __attribute__((ext_vector_type(8)))  _Float16  f16x8;

#define MFMA32(A, B, C) __builtin_amdgcn_mfma_f32_32x32x16_bf16(A, B, C, 0, 0, 0)

__device__ __forceinline__ unsigned short f2bf(float f) {
  union { float f; unsigned u; } x; x.f = f;
  return (unsigned short)((x.u + 0x7FFFu + ((x.u >> 16) & 1u)) >> 16);
}

__device__ __forceinline__ int cvtpk(float lo, float hi) {
  int r;
  asm("v_cvt_pk_bf16_f32 %0, %1, %2" : "=v"(r) : "v"(lo), "v"(hi));
  return r;
}

__device__ __forceinline__ i32x2 plswap(int a, int b) {
#if __has_builtin(__builtin_amdgcn_permlane32_swap)
  return __builtin_amdgcn_permlane32_swap(a, b, false, false);
#else
  int a2 = __shfl_xor(a, 32), b2 = __shfl_xor(b, 32);
  int hi = (threadIdx.x >> 5) & 1;
  i32x2 r; r.x = hi ? b2 : a; r.y = hi ? b : a2; return r;
#endif
}

__device__ __forceinline__ void gload16(const void* g, void* l) {
  __builtin_amdgcn_global_load_lds(
      (const __attribute__((address_space(1))) void*)g,
      (__attribute__((address_space(3))) void*)l, 16, 0, 0);
}

// ---------------------------------------------------------------------------
// Tile layout (K and V^T): 8KB tile = 32 LDS rows x 256B. Row r'=r&31 holds
// keys r' and r'+32; 16B slot = (((r>>5)<<3)+g) ^ (r&15). Conflict-free.
// ---------------------------------------------------------------------------
__global__ void prep_kv(const float* __restrict__ K, const float* __restrict__ V,
                        unsigned short* __restrict__ kb, unsigned short* __restrict__ vb) {
  if (blockIdx.x < 2048) {
    int gid = blockIdx.x * 256 + threadIdx.x;
    int g  = gid & 7;
    int s  = (gid >> 3) & (SEQ - 1);
    int bh = gid >> 14;
    int b = bh >> 3, h = bh & 7;
    const float* src = K + ((size_t)(b * SEQ + s) * DMODEL) + h * 64 + (g << 3);
    float4 a = ((const float4*)src)[0];
    float4 c = ((const float4*)src)[1];
    bf16x8 w;
    w[0] = (short)f2bf(a.x); w[1] = (short)f2bf(a.y);
    w[2] = (short)f2bf(a.z); w[3] = (short)f2bf(a.w);
    w[4] = (short)f2bf(c.x); w[5] = (short)f2bf(c.y);
    w[6] = (short)f2bf(c.z); w[7] = (short)f2bf(c.w);
    int r = s & 63;
    int slot = ((((r >> 5) << 3) + g) ^ (r & 15));
    unsigned short* dst = kb + ((size_t)bh * SEQ + (s & ~63)) * 64
                             + ((r & 31) << 7) + (slot << 3);
    *(bf16x8*)dst = w;
  } else {
    int bt = blockIdx.x - 2048;     // bh*32 + tile
    int bh = bt >> 5, tile = bt & 31;
    int b = bh >> 3, h = bh & 7;
    int t  = threadIdx.x;
    int d  = t & 63;
    int kg = t >> 6;
    const float* src = V + ((size_t)(b * SEQ + tile * 64 + kg * 16) * DMODEL) + h * 64 + d;
    float v[16];
#pragma unroll
    for (int j = 0; j < 16; ++j) v[j] = src[(size_t)j * DMODEL];
    bf16x8 lo, hi;
#pragma unroll
    for (int j = 0; j < 8; ++j) { lo[j] = (short)f2bf(v[j]); hi[j] = (short)f2bf(v[8 + j]); }
    unsigned short* base = vb + ((size_t)bt << 12);
    int g0 = kg << 1, g1 = (kg << 1) | 1;
    int rb = (((d >> 5) << 3));
    int s0 = ((rb + g0) ^ (d & 15));
    int s1 = ((rb + g1) ^ (d & 15));
    unsigned short* row = base + ((d & 31) << 7);
    *(bf16x8*)(row + (s0 << 3)) = lo;
    *(bf16x8*)(row + (s1 << 3)) = hi;
  }
}

// ------------------- shared per-tile machinery (macro-free core) ------------
#define STAGE_BODY(T, B)                                                   \
  do {                                                                     \
    const char* gk = (const char*)(Kh + (size_t)(T) * KVB * 64);           \
    const char* gv = (const char*)(Vh + (size_t)(T) * KVB * 64);           \
    char* lk = (char*)&kt[(B)][0];                                         \
    char* lv = (char*)&vt[(B)][0];                                         \
    gload16(gk + (((wv)     * 64 + ln) << 4), lk + ((wv)     << 10));      \
    gload16(gk + (((wv + 4) * 64 + ln) << 4), lk + ((wv + 4) << 10));      \
    gload16(gv + (((wv)     * 64 + ln) << 4), lv + ((wv)     << 10));      \
    gload16(gv + (((wv + 4) * 64 + ln) << 4), lv + ((wv + 4) << 10));      \
  } while (0)

// ------------------------- split-KV main kernel -----------------------------
__global__ __launch_bounds__(256, 4)
void fa_fwd_split(const float* __restrict__ Q, const unsigned short* __restrict__ Kb,
                  const unsigned short* __restrict__ Vb,
                  _Float16* __restrict__ opart, float2* __restrict__ ml) {
  __shared__ unsigned short kt[2][KVB * 64];
  __shared__ unsigned short vt[2][64 * KVB];

  const int tid = threadIdx.x;
  const int wv  = tid >> 6;
  const int ln  = tid & 63;
  const int l31 = ln & 31;
  const int hi  = ln >> 5;

  // XCD-chunked swizzle: 1024 blocks -> XCD x gets bh 4x..4x+3 (both halves)
  const int orig = blockIdx.x;
  const int wgid = (orig & 7) * 128 + (orig >> 3);
  const int bh   = wgid >> 5;
  const int qt   = (wgid >> 1) & 15;
  const int half = wgid & 1;
  const int b = bh >> 3, h = bh & 7;

  const float* Qh = Q + (size_t)b * SEQ * DMODEL + (size_t)h * 64;
  const unsigned short* Kh = Kb + (size_t)bh * SEQ * 64 + (size_t)half * NT_H * KVB * 64;
  const unsigned short* Vh = Vb + (size_t)bh * SEQ * 64 + (size_t)half * NT_H * KVB * 64;

  const int qrow = qt * QBLK + wv * 32 + l31;

  bf16x8 qf[4];
  {
    const float* qp = Qh + (size_t)qrow * DMODEL + (hi << 3);
#pragma unroll
    for (int t = 0; t < 4; ++t) {
      float4 a = *(const float4*)(qp + 16 * t);
      float4 c = *(const float4*)(qp + 16 * t + 4);
      bf16x8 w;
      w[0] = (short)f2bf(a.x * QSCALE); w[1] = (short)f2bf(a.y * QSCALE);
      w[2] = (short)f2bf(a.z * QSCALE); w[3] = (short)f2bf(a.w * QSCALE);
      w[4] = (short)f2bf(c.x * QSCALE); w[5] = (short)f2bf(c.y * QSCALE);
      w[6] = (short)f2bf(c.z * QSCALE); w[7] = (short)f2bf(c.w * QSCALE);
      qf[t] = w;
    }
  }

  const int rowb = l31 << 7;
  int ca[4], cb[4];
#pragma unroll
  for (int t = 0; t < 4; ++t) {
    int g = 2 * t + hi;
    ca[t] = rowb + (((g)     ^ (l31 & 15)) << 3);
    cb[t] = rowb + (((8 + g) ^ (l31 & 15)) << 3);
  }

  f32x16 o0 = {}, o1 = {};
  float m = -__builtin_inff();
  float l = 0.f;

  auto tile_compute = [&](const unsigned short* ktb, const unsigned short* vtb) {
    f32x16 s0 = {}, s1 = {};
#pragma unroll
    for (int ks = 0; ks < 4; ++ks) {
      bf16x8 k0 = *(const bf16x8*)&ktb[ca[ks]];
      bf16x8 k1 = *(const bf16x8*)&ktb[cb[ks]];
      __builtin_amdgcn_s_setprio(1);
      s0 = MFMA32(k0, qf[ks], s0);
      s1 = MFMA32(k1, qf[ks], s1);
      __builtin_amdgcn_s_setprio(0);
    }

    float pm = fmaxf(s0[0], s0[1]);
#pragma unroll
    for (int j = 2; j < 16; ++j) pm = fmaxf(pm, s0[j]);
#pragma unroll
    for (int j = 0; j < 16; ++j) pm = fmaxf(pm, s1[j]);
    pm = fmaxf(pm, __shfl_xor(pm, 32));

    if (__any(pm > m + THR)) {
      float mn   = fmaxf(m, pm);
      float corr = EXPFN(m - mn);
      m = mn;
      l *= corr;
#pragma unroll
      for (int j = 0; j < 16; ++j) { o0[j] *= corr; o1[j] *= corr; }
    }

#pragma unroll
    for (int ks = 0; ks < 4; ++ks) {
      float e[8];
#pragma unroll
      for (int j = 0; j < 8; ++j) {
        float sv = (ks < 2) ? s0[(ks & 1) * 8 + j] : s1[(ks & 1) * 8 + j];
        e[j] = EXPFN(sv - m);
      }
      l += ((e[0] + e[1]) + (e[2] + e[3])) + ((e[4] + e[5]) + (e[6] + e[7]));
      i32x2 r0 = plswap(cvtpk(e[0], e[1]), cvtpk(e[4], e[5]));
      i32x2 r1 = plswap(cvtpk(e[2], e[3]), cvtpk(e[6], e[7]));
      union { int i[4]; bf16x8 v; } pa;
      pa.i[0] = r0.x; pa.i[1] = r1.x; pa.i[2] = r0.y; pa.i[3] = r1.y;

      bf16x8 v0 = *(const bf16x8*)&vtb[ca[ks]];
      bf16x8 v1 = *(const bf16x8*)&vtb[cb[ks]];
      __builtin_amdgcn_s_setprio(1);
      o0 = MFMA32(v0, pa.v, o0);
      o1 = MFMA32(v1, pa.v, o1);
      __builtin_amdgcn_s_setprio(0);
    }
  };

  STAGE_BODY(0, 0);
  __syncthreads();
  for (int t = 0; t < NT_H; t += 2) {
    STAGE_BODY(t + 1, 1);              // t+1 <= 15, always valid
    tile_compute(kt[0], vt[0]);
    __syncthreads();
    if (t + 2 < NT_H) STAGE_BODY(t + 2, 0);
    tile_compute(kt[1], vt[1]);
    __syncthreads();
  }

  // ---- epilogue: per-half normalized O (f16) + (m, l) ----
  l += __shfl_xor(l, 32);
  float rinv = 1.0f / l;
  const size_t row = (size_t)bh * SEQ + qrow;
  if (hi == 0) ml[(size_t)half * 32 * SEQ + row] = float2{m, l};
  _Float16* op = opart + (size_t)half * 32 * SEQ * 64 + row * 64;
#pragma unroll
  for (int r4 = 0; r4 < 4; ++r4) {
    f16x4 w0, w1;
#pragma unroll
    for (int j = 0; j < 4; ++j) {
      w0[j] = (_Float16)(o0[4 * r4 + j] * rinv);
      w1[j] = (_Float16)(o1[4 * r4 + j] * rinv);
    }
    *(f16x4*)(op + 8 * r4 + 4 * hi)      = w0;
    *(f16x4*)(op + 32 + 8 * r4 + 4 * hi) = w1;
  }
}

// ------------------------- combine kernel -----------------------------------
__global__ __launch_bounds__(256)
void fa_combine(const _Float16* __restrict__ opart, const float2* __restrict__ ml,
                float* __restrict__ O) {
  int idx  = blockIdx.x * 256 + threadIdx.x;   // 0 .. 524287
  int dg   = idx & 7;                          // 8 d-elems each
  int qrow = (idx >> 3) & (SEQ - 1);
  int bh   = idx >> 14;                        // 0..31
  size_t row = (size_t)bh * SEQ + qrow;

  float2 a = ml[row];
  float2 c = ml[(size_t)32 * SEQ + row];
  float M  = fmaxf(a.x, c.x);
  float w1 = a.y * EXPFN(a.x - M);
  float w2 = c.y * EXPFN(c.x - M);
  float inv = 1.0f / (w1 + w2);
  w1 *= inv; w2 *= inv;

  f16x8 h1 = *(const f16x8*)(opart + row * 64 + dg * 8);
  f16x8 h2 = *(const f16x8*)(opart + (size_t)32 * SEQ * 64 + row * 64 + dg * 8);

  int b = bh >> 3, h = bh & 7;
  float* out = O + ((size_t)(b * SEQ + qrow)) * DMODEL + h * 64 + dg * 8;
  float4 v0, v1;
  v0.x = w1 * (float)h1[0] + w2 * (float)h2[0];
  v0.y = w1 * (float)h1[1] + w2 * (float)h2[1];
  v0.z = w1 * (float)h1[2] + w2 * (float)h2[2];
  v0.w = w1 * (float)h1[3] + w2 * (float)h2[3];
  v1.x = w1 * (float)h1[4] + w2 * (float)h2[4];
  v1.y = w1 * (float)h1[5] + w2 * (float)h2[5];
  v1.z = w1 * (float)h1[6] + w2 * (float)h2[6];
  v1.w = w1 * (float)h1[7] + w2 * (float)h2[7];
  ((float4*)out)[0] = v0;
  ((float4*)out)[1] = v1;
}

// ------------------- fallback: full-KV kernel (R4 structure) ----------------
__global__ __launch_bounds__(256, 2)
void fa_fwd(const float* __restrict__ Q, const unsigned short* __restrict__ Kb,
            const unsigned short* __restrict__ Vb, float* __restrict__ O) {
  __shared__ unsigned short kt[2][KVB * 64];
  __shared__ unsigned short vt[2][64 * KVB];

  const int tid = threadIdx.x;
  const int wv  = tid >> 6;
  const int ln  = tid & 63;
  const int l31 = ln & 31;
  const int hi  = ln >> 5;

  const int orig = blockIdx.x;
  const int wgid = (orig & 7) * 64 + (orig >> 3);
  const int bh = wgid >> 4;
  const int qt = wgid & 15;
  const int b = bh >> 3, h = bh & 7;

  const float* Qh = Q + (size_t)b * SEQ * DMODEL + (size_t)h * 64;
  float*       Oh = O + (size_t)b * SEQ * DMODEL + (size_t)h * 64;
  const unsigned short* Kh = Kb + (size_t)bh * SEQ * 64;
  const unsigned short* Vh = Vb + (size_t)bh * SEQ * 64;

  const int q = qt * QBLK + wv * 32 + l31;

  bf16x8 qf[4];
  {
    const float* qp = Qh + (size_t)q * DMODEL + (hi << 3);
#pragma unroll
    for (int t = 0; t < 4; ++t) {
      float4 a = *(const float4*)(qp + 16 * t);
      float4 c = *(const float4*)(qp + 16 * t + 4);
      bf16x8 w;
      w[0] = (short)f2bf(a.x * QSCALE); w[1] = (short)f2bf(a.y * QSCALE);
      w[2] = (short)f2bf(a.z * QSCALE); w[3] = (short)f2bf(a.w * QSCALE);
      w[4] = (short)f2bf(c.x * QSCALE); w[5] = (short)f2bf(c.y * QSCALE);
      w[6] = (short)f2bf(c.z * QSCALE); w[7] = (short)f2bf(c.w * QSCALE);
      qf[t] = w;
    }
  }

  const int rowb = l31 << 7;
  int ca[4], cb[4];
#pragma unroll
  for (int t = 0; t < 4; ++t) {
    int g = 2 * t + hi;
    ca[t] = rowb + (((g)     ^ (l31 & 15)) << 3);
    cb[t] = rowb + (((8 + g) ^ (l31 & 15)) << 3);
  }

  f32x16 o0 = {}, o1 = {};
  float m = -__builtin_inff();
  float l = 0.f;

  auto tile_compute = [&](const unsigned short* ktb, const unsigned short* vtb) {
    f32x16 s0 = {}, s1 = {};
#pragma unroll
    for (int ks = 0; ks < 4; ++ks) {
      bf16x8 k0 = *(const bf16x8*)&ktb[ca[ks]];
      bf16x8 k1 = *(const bf16x8*)&ktb[cb[ks]];
      __builtin_amdgcn_s_setprio(1);
      s0 = MFMA32(k0, qf[ks], s0);
      s1 = MFMA32(k1, qf[ks], s1);
      __builtin_amdgcn_s_setprio(0);
    }
    float pm = fmaxf(s0[0], s0[1]);
#pragma unroll
    for (int j = 2; j < 16; ++j) pm = fmaxf(pm, s0[j]);
#pragma unroll
    for (int j = 0; j < 16; ++j) pm = fmaxf(pm, s1[j]);
    pm = fmaxf(pm, __shfl_xor(pm, 32));
    if (__any(pm > m + THR)) {
      float mn   = fmaxf(m, pm);
      float corr = EXPFN(m - mn);
      m = mn;
      l *= corr;
#pragma unroll
      for (int j = 0; j < 16; ++j) { o0[j] *= corr; o1[j] *= corr; }
    }
#pragma unroll
    for (int ks = 0; ks < 4; ++ks) {
      float e[8];
#pragma unroll
      for (int j = 0; j < 8; ++j) {
        float sv = (ks < 2) ? s0[(ks & 1) * 8 + j] : s1[(ks & 1) * 8 + j];
        e[j] = EXPFN(sv - m);
      }
      l += ((e[0] + e[1]) + (e[2] + e[3])) + ((e[4] + e[5]) + (e[6] + e[7]));
      i32x2 r0 = plswap(cvtpk(e[0], e[1]), cvtpk(e[4], e[5]));
      i32x2 r1 = plswap(cvtpk(e[2], e[3]), cvtpk(e[6], e[7]));
      union { int i[4]; bf16x8 v; } pa;
      pa.i[0] = r0.x; pa.i[1] = r1.x; pa.i[2] = r0.y; pa.i[3] = r1.y;
      bf16x8 v0 = *(const bf16x8*)&vtb[ca[ks]];
      bf16x8 v1 = *(const bf16x8*)&vtb[cb[ks]];
      __builtin_amdgcn_s_setprio(1);
      o0 = MFMA32(v0, pa.v, o0);
      o1 = MFMA32(v1, pa.v, o1);
      __builtin_amdgcn_s_setprio(0);
    }
  };

  STAGE_BODY(0, 0);
  __syncthreads();
  for (int t = 0; t < NT; t += 2) {
    STAGE_BODY(t + 1, 1);
    tile_compute(kt[0], vt[0]);
    __syncthreads();
    if (t + 2 < NT) STAGE_BODY(t + 2, 0);
    tile_compute(kt[1], vt[1]);
    __syncthreads();
  }

  l += __shfl_xor(l, 32);
  float rinv = 1.0f / l;
  float* op = Oh + (size_t)q * DMODEL;
#pragma unroll
  for (int r4 = 0; r4 < 4; ++r4) {
    float4 w0, w1;
    w0.x = o0[4 * r4 + 0] * rinv; w0.y = o0[4 * r4 + 1] * rinv;
    w0.z = o0[4 * r4 + 2] * rinv; w0.w = o0[4 * r4 + 3] * rinv;
    w1.x = o1[4 * r4 + 0] * rinv; w1.y = o1[4 * r4 + 1] * rinv;
    w1.z = o1[4 * r4 + 2] * rinv; w1.w = o1[4 * r4 + 3] * rinv;
    *(float4*)(op + 8 * r4 + 4 * hi)      = w0;
    *(float4*)(op + 32 + 8 * r4 + 4 * hi) = w1;
  }
}

extern "C" void kernel_launch(void* const* d_in, const int* in_sizes, int n_in,
                              void* d_out, int out_size, void* d_ws, size_t ws_size,
                              hipStream_t stream) {
  const float* Q = (const float*)d_in[0];
  const float* K = (const float*)d_in[1];
  const float* V = (const float*)d_in[2];
  float* O = (float*)d_out;

  unsigned short* kb = (unsigned short*)d_ws;
  unsigned short* vb = kb + (size_t)32 * SEQ * 64;          // +8 MB
  prep_kv<<<3072, 256, 0, stream>>>(K, V, kb, vb);

  const size_t base   = (size_t)2 * 32 * SEQ * 64 * sizeof(unsigned short);  // 16 MB
  const size_t needsp = base + (size_t)2 * 32 * SEQ * 64 * sizeof(_Float16)  // +16 MB
                              + (size_t)2 * 32 * SEQ * sizeof(float2);       // +1 MB
  if (ws_size >= needsp + (1u << 20)) {
    _Float16* opart = (_Float16*)((char*)d_ws + base);
    float2*   ml    = (float2*)((char*)d_ws + base +
                       (size_t)2 * 32 * SEQ * 64 * sizeof(_Float16));
    fa_fwd_split<<<1024, 256, 0, stream>>>(Q, kb, vb, opart, ml);
    fa_combine<<<2048, 256, 0, stream>>>(opart, ml, O);
  } else {
    fa_fwd<<<512, 256, 0, stream>>>(Q, kb, vb, O);
  }
}

// Round 7
// 63.063 us; speedup vs baseline: 1.1195x; 1.1195x over previous
//
#include <hip/hip_runtime.h>
#include <hip/hip_bf16.h>

#define SEQ    2048
#define DMODEL 512
#define NH     8
#define QBLK   128   /* 4 waves x 32 q-rows */
#define KVB    64
#define NT     (SEQ / KVB)

#if __has_builtin(__builtin_amdgcn_exp2f)
#define EXPFN(x) __builtin_amdgcn_exp2f(x)
#define QSCALE 0.18033688011112042f   /* 0.125 * log2(e) */
#else
#define EXPFN(x) __expf(x)
#define QSCALE 0.125f
#endif
#define THR 8.0f

typedef __attribute__((ext_vector_type(8)))  short     bf16x8;
typedef __attribute__((ext_vector_type(16))) float     f32x16;
typedef __attribute__((ext_vector_type(2)))  int       i32x2;

#define MFMA32(A, B, C) __builtin_amdgcn_mfma_f32_32x32x16_bf16(A, B, C, 0, 0, 0)
#define VMCNT(n) asm volatile("s_waitcnt vmcnt(" #n ")" ::: "memory")

__device__ __forceinline__ unsigned short f2bf(float f) {
  union { float f; unsigned u; } x; x.f = f;
  return (unsigned short)((x.u + 0x7FFFu + ((x.u >> 16) & 1u)) >> 16);
}

__device__ __forceinline__ int cvtpk(float lo, float hi) {
  int r;
  asm("v_cvt_pk_bf16_f32 %0, %1, %2" : "=v"(r) : "v"(lo), "v"(hi));
  return r;
}

__device__ __forceinline__ i32x2 plswap(int a, int b) {
#if __has_builtin(__builtin_amdgcn_permlane32_swap)
  return __builtin_amdgcn_permlane32_swap(a, b, false, false);
#else
  int a2 = __shfl_xor(a, 32), b2 = __shfl_xor(b, 32);
  int hi = (threadIdx.x >> 5) & 1;
  i32x2 r; r.x = hi ? b2 : a; r.y = hi ? b : a2; return r;
#endif
}

__device__ __forceinline__ void gload16(const void* g, void* l) {
  __builtin_amdgcn_global_load_lds(
      (const __attribute__((address_space(1))) void*)g,
      (__attribute__((address_space(3))) void*)l, 16, 0, 0);
}

// ---------------------------------------------------------------------------
// Tile layout (K and V^T): 8KB tile = 32 LDS rows x 256B. Row r'=r&31 holds
// keys r' and r'+32; 16B slot = (((r>>5)<<3)+g) ^ (r&15). Conflict-free.
// ---------------------------------------------------------------------------
__global__ void prep_kv(const float* __restrict__ K, const float* __restrict__ V,
                        unsigned short* __restrict__ kb, unsigned short* __restrict__ vb) {
  if (blockIdx.x < 2048) {
    int gid = blockIdx.x * 256 + threadIdx.x;
    int g  = gid & 7;
    int s  = (gid >> 3) & (SEQ - 1);
    int bh = gid >> 14;
    int b = bh >> 3, h = bh & 7;
    const float* src = K + ((size_t)(b * SEQ + s) * DMODEL) + h * 64 + (g << 3);
    float4 a = ((const float4*)src)[0];
    float4 c = ((const float4*)src)[1];
    bf16x8 w;
    w[0] = (short)f2bf(a.x); w[1] = (short)f2bf(a.y);
    w[2] = (short)f2bf(a.z); w[3] = (short)f2bf(a.w);
    w[4] = (short)f2bf(c.x); w[5] = (short)f2bf(c.y);
    w[6] = (short)f2bf(c.z); w[7] = (short)f2bf(c.w);
    int r = s & 63;
    int slot = ((((r >> 5) << 3) + g) ^ (r & 15));
    unsigned short* dst = kb + ((size_t)bh * SEQ + (s & ~63)) * 64
                             + ((r & 31) << 7) + (slot << 3);
    *(bf16x8*)dst = w;
  } else {
    int bt = blockIdx.x - 2048;     // bh*32 + tile
    int bh = bt >> 5, tile = bt & 31;
    int b = bh >> 3, h = bh & 7;
    int t  = threadIdx.x;
    int d  = t & 63;
    int kg = t >> 6;
    const float* src = V + ((size_t)(b * SEQ + tile * 64 + kg * 16) * DMODEL) + h * 64 + d;
    float v[16];
#pragma unroll
    for (int j = 0; j < 16; ++j) v[j] = src[(size_t)j * DMODEL];
    bf16x8 lo, hi;
#pragma unroll
    for (int j = 0; j < 8; ++j) { lo[j] = (short)f2bf(v[j]); hi[j] = (short)f2bf(v[8 + j]); }
    unsigned short* base = vb + ((size_t)bt << 12);
    int g0 = kg << 1, g1 = (kg << 1) | 1;
    int rb = (((d >> 5) << 3));
    int s0 = ((rb + g0) ^ (d & 15));
    int s1 = ((rb + g1) ^ (d & 15));
    unsigned short* row = base + ((d & 31) << 7);
    *(bf16x8*)(row + (s0 << 3)) = lo;
    *(bf16x8*)(row + (s1 << 3)) = hi;
  }
}

// ---------------------------- main attention --------------------------------
// Counted-vmcnt pipeline (T3/T4): 4-buffer ring, prefetch distance 2,
// raw s_barrier with vmcnt(8) -- staging loads stay in flight across barriers.
__global__ __launch_bounds__(256, 2)
void fa_fwd(const float* __restrict__ Q, const unsigned short* __restrict__ Kb,
            const unsigned short* __restrict__ Vb, float* __restrict__ O) {
  __shared__ unsigned short kt[4][KVB * 64];
  __shared__ unsigned short vt[4][64 * KVB];

  const int tid = threadIdx.x;
  const int wv  = tid >> 6;
  const int ln  = tid & 63;
  const int l31 = ln & 31;
  const int hi  = ln >> 5;

  // XCD-chunked swizzle (512 blocks, 64 per XCD -> 4 heads per XCD L2)
  const int orig = blockIdx.x;
  const int wgid = (orig & 7) * 64 + (orig >> 3);
  const int bh = wgid >> 4;
  const int qt = wgid & 15;
  const int b = bh >> 3, h = bh & 7;

  const float* Qh = Q + (size_t)b * SEQ * DMODEL + (size_t)h * 64;
  float*       Oh = O + (size_t)b * SEQ * DMODEL + (size_t)h * 64;
  const unsigned short* Kh = Kb + (size_t)bh * SEQ * 64;
  const unsigned short* Vh = Vb + (size_t)bh * SEQ * 64;

  const int q = qt * QBLK + wv * 32 + l31;

  // ---- Q fragments: lane holds Q[q][16t+8hi+j], j=0..7 ----
  bf16x8 qf[4];
  {
    const float* qp = Qh + (size_t)q * DMODEL + (hi << 3);
#pragma unroll
    for (int t = 0; t < 4; ++t) {
      float4 a = *(const float4*)(qp + 16 * t);
      float4 c = *(const float4*)(qp + 16 * t + 4);
      bf16x8 w;
      w[0] = (short)f2bf(a.x * QSCALE); w[1] = (short)f2bf(a.y * QSCALE);
      w[2] = (short)f2bf(a.z * QSCALE); w[3] = (short)f2bf(a.w * QSCALE);
      w[4] = (short)f2bf(c.x * QSCALE); w[5] = (short)f2bf(c.y * QSCALE);
      w[6] = (short)f2bf(c.z * QSCALE); w[7] = (short)f2bf(c.w * QSCALE);
      qf[t] = w;
    }
  }

  const int rowb = l31 << 7;
  int ca[4], cb[4];
#pragma unroll
  for (int t = 0; t < 4; ++t) {
    int g = 2 * t + hi;
    ca[t] = rowb + (((g)     ^ (l31 & 15)) << 3);   // tile rows 0..31
    cb[t] = rowb + (((8 + g) ^ (l31 & 15)) << 3);   // tile rows 32..63
  }

  f32x16 o0 = {}, o1 = {};
  float m = -__builtin_inff();
  float l = 0.f;

  // 4 gload_lds (VMEM ops) per wave per STAGE
#define STAGE(T, B)                                                        \
  do {                                                                     \
    const char* gk = (const char*)(Kh + (size_t)(T) * KVB * 64);           \
    const char* gv = (const char*)(Vh + (size_t)(T) * KVB * 64);           \
    char* lk = (char*)&kt[(B)][0];                                         \
    char* lv = (char*)&vt[(B)][0];                                         \
    gload16(gk + (((wv)     * 64 + ln) << 4), lk + ((wv)     << 10));      \
    gload16(gk + (((wv + 4) * 64 + ln) << 4), lk + ((wv + 4) << 10));      \
    gload16(gv + (((wv)     * 64 + ln) << 4), lv + ((wv)     << 10));      \
    gload16(gv + (((wv + 4) * 64 + ln) << 4), lv + ((wv + 4) << 10));      \
  } while (0)

  auto tile_compute = [&](const unsigned short* ktb, const unsigned short* vtb) {
    f32x16 s0 = {}, s1 = {};
#pragma unroll
    for (int ks = 0; ks < 4; ++ks) {
      bf16x8 k0 = *(const bf16x8*)&ktb[ca[ks]];
      bf16x8 k1 = *(const bf16x8*)&ktb[cb[ks]];
      __builtin_amdgcn_s_setprio(1);
      s0 = MFMA32(k0, qf[ks], s0);
      s1 = MFMA32(k1, qf[ks], s1);
      __builtin_amdgcn_s_setprio(0);
    }

    float pm = fmaxf(s0[0], s0[1]);
#pragma unroll
    for (int j = 2; j < 16; ++j) pm = fmaxf(pm, s0[j]);
#pragma unroll
    for (int j = 0; j < 16; ++j) pm = fmaxf(pm, s1[j]);
    pm = fmaxf(pm, __shfl_xor(pm, 32));

    if (__any(pm > m + THR)) {
      float mn   = fmaxf(m, pm);
      float corr = EXPFN(m - mn);
      m = mn;
      l *= corr;
#pragma unroll
      for (int j = 0; j < 16; ++j) { o0[j] *= corr; o1[j] *= corr; }
    }

#pragma unroll
    for (int ks = 0; ks < 4; ++ks) {
      float e[8];
#pragma unroll
      for (int j = 0; j < 8; ++j) {
        float sv = (ks < 2) ? s0[(ks & 1) * 8 + j] : s1[(ks & 1) * 8 + j];
        e[j] = EXPFN(sv - m);
      }
      l += ((e[0] + e[1]) + (e[2] + e[3])) + ((e[4] + e[5]) + (e[6] + e[7]));
      i32x2 r0 = plswap(cvtpk(e[0], e[1]), cvtpk(e[4], e[5]));
      i32x2 r1 = plswap(cvtpk(e[2], e[3]), cvtpk(e[6], e[7]));
      union { int i[4]; bf16x8 v; } pa;
      pa.i[0] = r0.x; pa.i[1] = r1.x; pa.i[2] = r0.y; pa.i[3] = r1.y;

      bf16x8 v0 = *(const bf16x8*)&vtb[ca[ks]];
      bf16x8 v1 = *(const bf16x8*)&vtb[cb[ks]];
      __builtin_amdgcn_s_setprio(1);
      o0 = MFMA32(v0, pa.v, o0);
      o1 = MFMA32(v1, pa.v, o1);
      __builtin_amdgcn_s_setprio(0);
    }
  };

  // ITER: stage t+2, wait ONLY until tile t's 4 loads retired (8 newest still
  // in flight), raw barrier, then compute. No vmcnt(0) drain in the loop.
#define ITER_FULL(T, BS, BC)                                               \
  do {                                                                     \
    STAGE((T) + 2, BS);                                                    \
    __builtin_amdgcn_sched_barrier(0);                                     \
    VMCNT(8);                                                              \
    __builtin_amdgcn_s_barrier();                                          \
    __builtin_amdgcn_sched_barrier(0);                                     \
    tile_compute(kt[BC], vt[BC]);                                          \
  } while (0)

  // prologue: pin Q-load consumption before the counted region
  __builtin_amdgcn_sched_barrier(0);
  STAGE(0, 0);
  STAGE(1, 1);

  for (int t = 0; t < NT - 4; t += 4) {
    ITER_FULL(t + 0, 2, 0);
    ITER_FULL(t + 1, 3, 1);
    ITER_FULL(t + 2, 0, 2);
    ITER_FULL(t + 3, 1, 3);
  }
  // epilogue tiles 28..31
  ITER_FULL(NT - 4, 2, 0);
  ITER_FULL(NT - 3, 3, 1);
  __builtin_amdgcn_sched_barrier(0);
  VMCNT(4);
  __builtin_amdgcn_s_barrier();
  __builtin_amdgcn_sched_barrier(0);
  tile_compute(kt[2], vt[2]);
  __builtin_amdgcn_sched_barrier(0);
  VMCNT(0);
  __builtin_amdgcn_s_barrier();
  __builtin_amdgcn_sched_barrier(0);
  tile_compute(kt[3], vt[3]);

  // ---- epilogue ----
  l += __shfl_xor(l, 32);
  float rinv = 1.0f / l;
  float* op = Oh + (size_t)q * DMODEL;
#pragma unroll
  for (int r4 = 0; r4 < 4; ++r4) {
    float4 w0, w1;
    w0.x = o0[4 * r4 + 0] * rinv; w0.y = o0[4 * r4 + 1] * rinv;
    w0.z = o0[4 * r4 + 2] * rinv; w0.w = o0[4 * r4 + 3] * rinv;
    w1.x = o1[4 * r4 + 0] * rinv; w1.y = o1[4 * r4 + 1] * rinv;
    w1.z = o1[4 * r4 + 2] * rinv; w1.w = o1[4 * r4 + 3] * rinv;
    *(float4*)(op + 8 * r4 + 4 * hi)      = w0;
    *(float4*)(op + 32 + 8 * r4 + 4 * hi) = w1;
  }
}

extern "C" void kernel_launch(void* const* d_in, const int* in_sizes, int n_in,
                              void* d_out, int out_size, void* d_ws, size_t ws_size,
                              hipStream_t stream) {
  const float* Q = (const float*)d_in[0];
  const float* K = (const float*)d_in[1];
  const float* V = (const float*)d_in[2];
  float* O = (float*)d_out;
  unsigned short* kb = (unsigned short*)d_ws;
  unsigned short* vb = kb + (size_t)32 * SEQ * 64;
  prep_kv<<<3072, 256, 0, stream>>>(K, V, kb, vb);
  fa_fwd<<<512, 256, 0, stream>>>(Q, kb, vb, O);
}